// Round 13
// baseline (57.880 us; speedup 1.0000x reference)
//
#include <hip/hip_runtime.h>

// ZBL repulsion energy: out[b] = sum_{n,k} KEHALF * f(a*d) * Zi*Zj*mask / d
// B=16, N=8192, K=128 in the bench (shapes derived from in_sizes).
//
// Round-13: discriminating experiment — NO LDS ring, NO global_load_lds.
// Stream {idx,mask,dist} straight to REGISTERS (2 edges/lane, int2/float2/
// float2), explicit depth-2 A/B rotation with per-iteration issue (compiler
// inserts counted vmcnt). LDS holds ONLY the 16KB atom tab for the gather.
//  - 256-thr blocks, __launch_bounds__(256,8) -> VGPR<=64, 8 blocks/CU,
//    32 waves/CU. ITERS=16 -> grid (128,B) = 2048 blocks = exactly 8/CU.
//  - row atom read is lane-uniform (K>=128): broadcast ds_read.
// R7-R12 post-mortem: per-wave throughput fell 3.4x going 8->32 waves/CU
// in the DMA-ring family => shared-resource contention on the DMA->LDS->
// ds_read path. This kernel removes that path entirely.

#define KEHALF_F 7.199822675975274f
#define LOG2E_F  1.4426950408889634f
#define WPB   4        // waves per block (256 threads)
#define EPI   128      // edges per wave-iteration (2 per lane)
#define ITERS 16       // per-wave span = 2048 edges

__device__ __forceinline__ float softplus_f(float x) {
    return (x > 20.f) ? x : log1pf(__expf(x));
}

// ---------------- precompute: scalars + packed u16 per-atom table ----------------
// scal: [5..8]=e_i(=-sp(a_i)*log2e) [9]=qb [10]=qs [11..14]=log2(w_i*KEHALF)
__global__ void zbl_pre(const int* __restrict__ zn,
                        const float* __restrict__ adiv,
                        const float* __restrict__ apow,
                        const float* __restrict__ c1, const float* __restrict__ c2,
                        const float* __restrict__ c3, const float* __restrict__ c4,
                        const float* __restrict__ a1, const float* __restrict__ a2,
                        const float* __restrict__ a3, const float* __restrict__ a4,
                        unsigned short* __restrict__ packed, float* __restrict__ scal,
                        int total_atoms)
{
    int i = blockIdx.x * blockDim.x + threadIdx.x;
    const float spa = softplus_f(apow[0]);
    const float sad = softplus_f(adiv[0]);
    const float qb  = sad;                                  // Z=1 -> zps=sad
    const float qmax = sad * __expf(spa * __logf(94.f));
    const float qs  = (qmax - qb) * (1.f / 511.f);
    if (i == 0) {
        float s1 = softplus_f(c1[0]), s2 = softplus_f(c2[0]);
        float s3 = softplus_f(c3[0]), s4 = softplus_f(c4[0]);
        float inv = KEHALF_F / (s1 + s2 + s3 + s4);         // fold KEHALF
        float w1 = s1 * inv, w2 = s2 * inv, w3 = s3 * inv, w4 = s4 * inv;
        scal[0] = sad;
        scal[1] = w1; scal[2] = w2; scal[3] = w3; scal[4] = w4;
        scal[5] = -softplus_f(a1[0]) * LOG2E_F;             // exp2 exponents
        scal[6] = -softplus_f(a2[0]) * LOG2E_F;
        scal[7] = -softplus_f(a3[0]) * LOG2E_F;
        scal[8] = -softplus_f(a4[0]) * LOG2E_F;
        scal[9]  = qb;
        scal[10] = qs;
        scal[11] = __log2f(w1);                             // weight -> exponent
        scal[12] = __log2f(w2);
        scal[13] = __log2f(w3);
        scal[14] = __log2f(w4);
    }
    if (i < total_atoms) {
        unsigned int Z = (unsigned int)zn[i];
        float Zf = (float)Z;
        float zps = sad * __expf(spa * __logf(Zf));         // sp(adiv) * Z^sp(apow)
        float qf = (zps - qb) / qs;
        int q = (int)(qf + 0.5f);
        if (q < 0) q = 0;
        if (q > 511) q = 511;
        packed[i] = (unsigned short)(((unsigned)q << 7) | (Z & 0x7Fu));
    }
}

// ---------------- main: reg-streamed depth-2 pipeline + LDS tab gather ----------------
extern __shared__ unsigned short tab[];   // N u16

// compute both edges from stage regs; wi row is lane-uniform (K >= 128)
#define COMP(ii, i2, m2, d2) do {                                                 \
    const unsigned int wi_ = tab[(unsigned)(rw + (ii) * EPI) >> kshift];          \
    const unsigned int wj0 = tab[i2.x];                                           \
    const unsigned int wj1 = tab[i2.y];                                           \
    const float zpi = fmaf((float)(wi_ >> 7), qs, qb);                            \
    const float Zi  = (float)(wi_ & 0x7Fu);                                       \
    const float zpj0 = fmaf((float)(wj0 >> 7), qs, qb);                           \
    const float Zj0  = (float)(wj0 & 0x7Fu);                                      \
    const float zpj1 = fmaf((float)(wj1 >> 7), qs, qb);                           \
    const float Zj1  = (float)(wj1 & 0x7Fu);                                      \
    const float zz0 = Zi * Zj0 * m2.x;                                            \
    const float zz1 = Zi * Zj1 * m2.y;                                            \
    const float ad0 = (zpi + zpj0) * (m2.x * d2.x);                               \
    const float ad1 = (zpi + zpj1) * (m2.y * d2.y);                               \
    const float f0 = exp2f(fmaf(e1, ad0, l1)) + exp2f(fmaf(e2, ad0, l2))          \
                   + exp2f(fmaf(e3, ad0, l3)) + exp2f(fmaf(e4, ad0, l4));         \
    const float f1 = exp2f(fmaf(e1, ad1, l1)) + exp2f(fmaf(e2, ad1, l2))          \
                   + exp2f(fmaf(e3, ad1, l3)) + exp2f(fmaf(e4, ad1, l4));         \
    acc += f0 * zz0 * __builtin_amdgcn_rcpf(d2.x);                                \
    acc += f1 * zz1 * __builtin_amdgcn_rcpf(d2.y);                                \
} while (0)

#define LOAD(i2, m2, d2, ii) do {                                                 \
    i2 = *(const int2*)  (nb_ + (ii) * EPI + (lane << 1));                        \
    m2 = *(const float2*)(mk_ + (ii) * EPI + (lane << 1));                        \
    d2 = *(const float2*)(ds_ + (ii) * EPI + (lane << 1));                        \
} while (0)

__global__ __launch_bounds__(256, 8) void zbl_main13(
        const int*            __restrict__ neighbors,
        const float*          __restrict__ mask,
        const float*          __restrict__ dist,
        const unsigned short* __restrict__ packed,
        const float*          __restrict__ scal,
        float*                __restrict__ out,
        int N, int kshift, int epb)
{
    __shared__ float wsum[WPB];

    const int tid  = threadIdx.x;
    const int w    = tid >> 6;
    const int lane = tid & 63;
    const int b    = blockIdx.y;

    // wave's contiguous edge span within batch b
    const int rw = (blockIdx.x * WPB + w) * (ITERS * EPI);
    const size_t ebase = (size_t)b * epb + (size_t)rw;
    const int*   nb_ = neighbors + ebase;
    const float* mk_ = mask      + ebase;
    const float* ds_ = dist      + ebase;

    // 1) tab global loads FIRST (oldest in vmem queue) — 4 uint4 per thread
    const uint4* s4 = (const uint4*)(packed + (size_t)b * N);
    const int n4 = N >> 3;                      // # of uint4 (<= 1024)
    uint4 tv0, tv1, tv2, tv3;
    const bool g0 = (tid       < n4);
    const bool g1 = (tid + 256 < n4);
    const bool g2 = (tid + 512 < n4);
    const bool g3 = (tid + 768 < n4);
    if (g0) tv0 = s4[tid];
    if (g1) tv1 = s4[tid + 256];
    if (g2) tv2 = s4[tid + 512];
    if (g3) tv3 = s4[tid + 768];

    // 2) streaming prologue: stages A=iter0, B=iter1 (newer than tab loads,
    //    so the tab LDS-write below waits only the tab loads — counted vmcnt)
    int2 iA, iB; float2 mA, dA, mB, dB;
    LOAD(iA, mA, dA, 0);
    LOAD(iB, mB, dB, 1);

    // 3) write tab to LDS, then barrier
    {
        uint4* t4 = (uint4*)tab;
        if (g0) t4[tid]       = tv0;
        if (g1) t4[tid + 256] = tv1;
        if (g2) t4[tid + 512] = tv2;
        if (g3) t4[tid + 768] = tv3;
    }
    const float e1 = scal[5],  e2 = scal[6],  e3 = scal[7],  e4 = scal[8];
    const float qb = scal[9],  qs = scal[10];
    const float l1 = scal[11], l2 = scal[12], l3 = scal[13], l4 = scal[14];
    __syncthreads();

    float acc = 0.f;

    // main loop: depth-2 A/B rotation, loads issued per-iteration.
    int it = 0;
    for (; it < ITERS - 3; it += 2) {
        COMP(it, iA, mA, dA);
        LOAD(iA, mA, dA, it + 2);
        COMP(it + 1, iB, mB, dB);
        LOAD(iB, mB, dB, it + 3);
    }
    COMP(ITERS - 2, iA, mA, dA);
    COMP(ITERS - 1, iB, mB, dB);

    // reduce: wave shuffle, then cross-wave via LDS, one atomic per block
    #pragma unroll
    for (int off = 32; off > 0; off >>= 1) acc += __shfl_down(acc, off);
    if (lane == 0) wsum[w] = acc;
    __syncthreads();
    if (tid == 0) {
        float t = 0.f;
        #pragma unroll
        for (int i = 0; i < WPB; ++i) t += wsum[i];
        atomicAdd(&out[b], t);
    }
}

// ---------------- fallback (generic shapes, not used in bench) ----------------
__global__ void zbl_fallback(const int* __restrict__ neighbors,
                             const float* __restrict__ mask,
                             const float* __restrict__ dist,
                             const unsigned short* __restrict__ packed,
                             const float* __restrict__ scal,
                             float* __restrict__ out,
                             int N, int K, int epb, int total_edges)
{
    const int e = blockIdx.x * blockDim.x + threadIdx.x;
    if (e >= total_edges) return;
    const float e1 = scal[5], e2 = scal[6], e3 = scal[7], e4 = scal[8];
    const float qb = scal[9], qs = scal[10];
    const float l1 = scal[11], l2 = scal[12], l3 = scal[13], l4 = scal[14];
    const int b = e / epb;
    const int n = (e - b * epb) / K;
    const unsigned int wi = packed[(size_t)b * N + n];
    const unsigned int wj = packed[(size_t)b * N + neighbors[e]];
    const float zpi = fmaf((float)(wi >> 7), qs, qb);
    const float zpj = fmaf((float)(wj >> 7), qs, qb);
    const float Zi = (float)(wi & 0x7Fu), Zj = (float)(wj & 0x7Fu);
    const float m = mask[e], d = dist[e];
    const float ad = (zpi + zpj) * (m * d);
    const float f = exp2f(fmaf(e1, ad, l1)) + exp2f(fmaf(e2, ad, l2))
                  + exp2f(fmaf(e3, ad, l3)) + exp2f(fmaf(e4, ad, l4));
    const float corr = (m != 0.f) ? (f * Zi * Zj * m / d) : 0.f;
    if (corr != 0.f) atomicAdd(&out[b], corr);
}

extern "C" void kernel_launch(void* const* d_in, const int* in_sizes, int n_in,
                              void* d_out, int out_size, void* d_ws, size_t ws_size,
                              hipStream_t stream) {
    const int*   neighbors = (const int*)  d_in[0];
    const float* nb_mask   = (const float*)d_in[1];
    const int*   zn        = (const int*)  d_in[2];
    const float* dist      = (const float*)d_in[3];
    const float* adiv = (const float*)d_in[4];
    const float* apow = (const float*)d_in[5];
    const float* c1 = (const float*)d_in[6];
    const float* c2 = (const float*)d_in[7];
    const float* c3 = (const float*)d_in[8];
    const float* c4 = (const float*)d_in[9];
    const float* a1 = (const float*)d_in[10];
    const float* a2 = (const float*)d_in[11];
    const float* a3 = (const float*)d_in[12];
    const float* a4 = (const float*)d_in[13];

    const int total_edges = in_sizes[0];   // B*N*K
    const int total_atoms = in_sizes[2];   // B*N
    const int B = out_size;                // [B,1] fp32 output
    const int N = total_atoms / B;
    const int K = total_edges / total_atoms;
    const int epb = N * K;

    float*          scal   = (float*)d_ws;                         // 15 f32
    unsigned short* packed = (unsigned short*)((char*)d_ws + 64);  // B*N u16

    hipMemsetAsync(d_out, 0, (size_t)out_size * sizeof(float), stream);

    {
        const int threads = 256;
        const int blocks = (total_atoms + threads - 1) / threads;
        zbl_pre<<<blocks, threads, 0, stream>>>(zn, adiv, apow, c1, c2, c3, c4,
                                                a1, a2, a3, a4,
                                                packed, scal, total_atoms);
    }

    int kshift = 0;
    while ((1 << kshift) < K && kshift < 30) kshift++;
    const bool kpow2 = ((1 << kshift) == K);

    const int span_block = WPB * EPI * ITERS;           // 8192 edges/block
    const bool fast = kpow2 && (kshift >= 7) && (N % 8 == 0) && (N <= 8192) &&
                      (epb % span_block == 0) &&
                      ((size_t)(64 + (size_t)total_atoms * 2) <= ws_size);
    if (fast) {
        const int bpb = epb / span_block;               // blocks per batch
        dim3 grid(bpb, B);
        zbl_main13<<<grid, 256, (size_t)N * 2, stream>>>(
            neighbors, nb_mask, dist, packed, scal, (float*)d_out,
            N, kshift, epb);
    } else {
        const int threads = 256;
        const int blocks = (total_edges + threads - 1) / threads;
        zbl_fallback<<<blocks, threads, 0, stream>>>(
            neighbors, nb_mask, dist, packed, scal, (float*)d_out,
            N, K, epb, total_edges);
    }
}

// Round 14
// 55.772 us; speedup vs baseline: 1.0378x; 1.0378x over previous
//
#include <hip/hip_runtime.h>

// ZBL repulsion energy: out[b] = sum_{n,k} KEHALF * f(a*d) * Zi*Zj*mask / d
// B=16, N=8192, K=128 in the bench (shapes derived from in_sizes).
//
// Round-14: DMA-request-rate hypothesis. R8's STAGE1 (48 lanes, 3 divergent
// 256B segments) = 3 small DMA requests per 64 edges. Here: 256-edge granule
// staged by 3 FULL-WIDTH global_load_lds (64 lanes x 16B = 1KB contiguous,
// one segment each) -> 4x fewer, 4x larger DMA requests per byte.
//  - slot 3KB = [1KB idx][1KB mask][1KB dist]; DEPTH=2; WPB=4 (256 thr).
//    LDS = 4*2*3072 + 16384 tab = 40960 exactly -> 4 blocks/CU, grid (64,16)
//    = 1024 blocks = 4 resident/CU (16 waves/CU).
//  - 4 consecutive edges per lane: slot reads = 3x ds_read_b128 (1/4 the LDS
//    instrs), compute = 4 independent chains (ILP covers halved wave count).
//  - steady s_waitcnt vmcnt(3) (next slot's 3 DMAs outstanding); epilogue 3/0.

#define KEHALF_F 7.199822675975274f
#define LOG2E_F  1.4426950408889634f
#define DEPTH    2
#define GRAN     256      // edges per wave-iteration (4 per lane)
#define WPB      4        // waves per block (256 threads)
#define SLOTB    3072     // 1KB idx + 1KB mask + 1KB dist
#define ITERS    16       // per-wave span = 4096 edges

__device__ __forceinline__ float softplus_f(float x) {
    return (x > 20.f) ? x : log1pf(__expf(x));
}

// ---------------- precompute: scalars + packed u16 per-atom table ----------------
// scal: [5..8]=e_i(=-sp(a_i)*log2e) [9]=qb [10]=qs [11..14]=log2(w_i*KEHALF)
__global__ void zbl_pre(const int* __restrict__ zn,
                        const float* __restrict__ adiv,
                        const float* __restrict__ apow,
                        const float* __restrict__ c1, const float* __restrict__ c2,
                        const float* __restrict__ c3, const float* __restrict__ c4,
                        const float* __restrict__ a1, const float* __restrict__ a2,
                        const float* __restrict__ a3, const float* __restrict__ a4,
                        unsigned short* __restrict__ packed, float* __restrict__ scal,
                        int total_atoms)
{
    int i = blockIdx.x * blockDim.x + threadIdx.x;
    const float spa = softplus_f(apow[0]);
    const float sad = softplus_f(adiv[0]);
    const float qb  = sad;                                  // Z=1 -> zps=sad
    const float qmax = sad * __expf(spa * __logf(94.f));
    const float qs  = (qmax - qb) * (1.f / 511.f);
    if (i == 0) {
        float s1 = softplus_f(c1[0]), s2 = softplus_f(c2[0]);
        float s3 = softplus_f(c3[0]), s4 = softplus_f(c4[0]);
        float inv = KEHALF_F / (s1 + s2 + s3 + s4);         // fold KEHALF
        float w1 = s1 * inv, w2 = s2 * inv, w3 = s3 * inv, w4 = s4 * inv;
        scal[0] = sad;
        scal[1] = w1; scal[2] = w2; scal[3] = w3; scal[4] = w4;
        scal[5] = -softplus_f(a1[0]) * LOG2E_F;             // exp2 exponents
        scal[6] = -softplus_f(a2[0]) * LOG2E_F;
        scal[7] = -softplus_f(a3[0]) * LOG2E_F;
        scal[8] = -softplus_f(a4[0]) * LOG2E_F;
        scal[9]  = qb;
        scal[10] = qs;
        scal[11] = __log2f(w1);                             // weight -> exponent
        scal[12] = __log2f(w2);
        scal[13] = __log2f(w3);
        scal[14] = __log2f(w4);
    }
    if (i < total_atoms) {
        unsigned int Z = (unsigned int)zn[i];
        float Zf = (float)Z;
        float zps = sad * __expf(spa * __logf(Zf));         // sp(adiv) * Z^sp(apow)
        float qf = (zps - qb) / qs;
        int q = (int)(qf + 0.5f);
        if (q < 0) q = 0;
        if (q > 511) q = 511;
        packed[i] = (unsigned short)(((unsigned)q << 7) | (Z & 0x7Fu));
    }
}

// ---------------- main: 1KB-request DMA ring, 4 edges/lane ----------------
extern __shared__ unsigned short tab[];   // N u16 (dynamic, after static)

// three full-width (64-lane x 16B) contiguous DMAs stage the 3KB slot
#define STAGE3(slotp, it) do {                                                    \
    const char* _gi = (const char*)(nb_ + ((it) << 8)) + lane * 16;               \
    const char* _gm = (const char*)(mk_ + ((it) << 8)) + lane * 16;               \
    const char* _gd = (const char*)(ds_ + ((it) << 8)) + lane * 16;               \
    __builtin_amdgcn_global_load_lds(                                             \
        (const __attribute__((address_space(1))) void*)_gi,                       \
        (__attribute__((address_space(3))) void*)(slotp), 16, 0, 0);              \
    __builtin_amdgcn_global_load_lds(                                             \
        (const __attribute__((address_space(1))) void*)_gm,                       \
        (__attribute__((address_space(3))) void*)((slotp) + 1024), 16, 0, 0);     \
    __builtin_amdgcn_global_load_lds(                                             \
        (const __attribute__((address_space(1))) void*)_gd,                       \
        (__attribute__((address_space(3))) void*)((slotp) + 2048), 16, 0, 0);     \
} while (0)

// read slot + compute 4 independent edges; row atom shared by the 4 (4|K)
#define BODY(it) do {                                                             \
    char* sp = &stage[w][(it) & (DEPTH - 1)][0];                                  \
    const int4   j4 = *(const int4*)  (sp + (lane << 4));                         \
    const float4 m4 = *(const float4*)(sp + 1024 + (lane << 4));                  \
    const float4 d4 = *(const float4*)(sp + 2048 + (lane << 4));                  \
    const int r = rw + ((it) << 8) + (lane << 2);                                 \
    const unsigned int wi_ = tab[(unsigned)r >> kshift];                          \
    const unsigned int wj0 = tab[j4.x];                                           \
    const unsigned int wj1 = tab[j4.y];                                           \
    const unsigned int wj2 = tab[j4.z];                                           \
    const unsigned int wj3 = tab[j4.w];                                           \
    const float zpi = fmaf((float)(wi_ >> 7), qs, qb);                            \
    const float Zi  = (float)(wi_ & 0x7Fu);                                       \
    const float zpj0 = fmaf((float)(wj0 >> 7), qs, qb), Zj0 = (float)(wj0 & 0x7Fu);\
    const float zpj1 = fmaf((float)(wj1 >> 7), qs, qb), Zj1 = (float)(wj1 & 0x7Fu);\
    const float zpj2 = fmaf((float)(wj2 >> 7), qs, qb), Zj2 = (float)(wj2 & 0x7Fu);\
    const float zpj3 = fmaf((float)(wj3 >> 7), qs, qb), Zj3 = (float)(wj3 & 0x7Fu);\
    const float ad0 = (zpi + zpj0) * (m4.x * d4.x);                               \
    const float ad1 = (zpi + zpj1) * (m4.y * d4.y);                               \
    const float ad2 = (zpi + zpj2) * (m4.z * d4.z);                               \
    const float ad3 = (zpi + zpj3) * (m4.w * d4.w);                               \
    const float f0 = exp2f(fmaf(e1, ad0, l1)) + exp2f(fmaf(e2, ad0, l2))          \
                   + exp2f(fmaf(e3, ad0, l3)) + exp2f(fmaf(e4, ad0, l4));         \
    const float f1 = exp2f(fmaf(e1, ad1, l1)) + exp2f(fmaf(e2, ad1, l2))          \
                   + exp2f(fmaf(e3, ad1, l3)) + exp2f(fmaf(e4, ad1, l4));         \
    const float f2 = exp2f(fmaf(e1, ad2, l1)) + exp2f(fmaf(e2, ad2, l2))          \
                   + exp2f(fmaf(e3, ad2, l3)) + exp2f(fmaf(e4, ad2, l4));         \
    const float f3 = exp2f(fmaf(e1, ad3, l1)) + exp2f(fmaf(e2, ad3, l2))          \
                   + exp2f(fmaf(e3, ad3, l3)) + exp2f(fmaf(e4, ad3, l4));         \
    acc += f0 * (Zi * Zj0 * m4.x) * __builtin_amdgcn_rcpf(d4.x);                  \
    acc += f1 * (Zi * Zj1 * m4.y) * __builtin_amdgcn_rcpf(d4.y);                  \
    acc += f2 * (Zi * Zj2 * m4.z) * __builtin_amdgcn_rcpf(d4.z);                  \
    acc += f3 * (Zi * Zj3 * m4.w) * __builtin_amdgcn_rcpf(d4.w);                  \
} while (0)

__global__ __launch_bounds__(256, 4) void zbl_main14(
        const int*            __restrict__ neighbors,
        const float*          __restrict__ mask,
        const float*          __restrict__ dist,
        const unsigned short* __restrict__ packed,
        const float*          __restrict__ scal,
        float*                __restrict__ out,
        int N, int kshift, int epb)
{
    __shared__ char stage[WPB][DEPTH][SLOTB];   // 24576 B static

    const int tid  = threadIdx.x;
    const int w    = tid >> 6;
    const int lane = tid & 63;
    const int b    = blockIdx.y;

    // wave's contiguous edge span within batch b
    const int rw = (blockIdx.x * WPB + w) * (ITERS * GRAN);
    const size_t ebase = (size_t)b * epb + (size_t)rw;
    const int*   nb_ = neighbors + ebase;
    const float* mk_ = mask      + ebase;
    const float* ds_ = dist      + ebase;

    // 1) tab global loads first (oldest in vmem queue) — 4 uint4/thread
    const uint4* s4 = (const uint4*)(packed + (size_t)b * N);
    const int n4 = N >> 3;                      // # of uint4 (<= 1024)
    uint4 tv0, tv1, tv2, tv3;
    const bool g0 = (tid       < n4);
    const bool g1 = (tid + 256 < n4);
    const bool g2 = (tid + 512 < n4);
    const bool g3 = (tid + 768 < n4);
    if (g0) tv0 = s4[tid];
    if (g1) tv1 = s4[tid + 256];
    if (g2) tv2 = s4[tid + 512];
    if (g3) tv3 = s4[tid + 768];

    // 2) ring prologue: issue DEPTH slots (3 DMAs each)
    {
        char* sp0 = &stage[w][0][0]; STAGE3(sp0, 0);
        char* sp1 = &stage[w][1][0]; STAGE3(sp1, 1);
    }

    // 3) write tab to LDS (counted wait on the older tab loads), barrier
    {
        uint4* t4 = (uint4*)tab;
        if (g0) t4[tid]       = tv0;
        if (g1) t4[tid + 256] = tv1;
        if (g2) t4[tid + 512] = tv2;
        if (g3) t4[tid + 768] = tv3;
    }
    const float e1 = scal[5],  e2 = scal[6],  e3 = scal[7],  e4 = scal[8];
    const float qb = scal[9],  qs = scal[10];
    const float l1 = scal[11], l2 = scal[12], l3 = scal[13], l4 = scal[14];
    __syncthreads();

    float acc = 0.f;
    int it = 0;

    // main loop: wait slot, read, drain reads, restage same slot for it+2
    for (; it <= ITERS - 3; ++it) {
        asm volatile("s_waitcnt vmcnt(3)" ::: "memory");     // slot 'it' landed
        char* sp = &stage[w][it & (DEPTH - 1)][0];
        const int4   j4 = *(const int4*)  (sp + (lane << 4));
        const float4 m4 = *(const float4*)(sp + 1024 + (lane << 4));
        const float4 d4 = *(const float4*)(sp + 2048 + (lane << 4));
        asm volatile("s_waitcnt lgkmcnt(0)" ::: "memory");   // slot consumed
        STAGE3(sp, it + 2);
        const int r = rw + (it << 8) + (lane << 2);
        const unsigned int wi_ = tab[(unsigned)r >> kshift];
        const unsigned int wj0 = tab[j4.x];
        const unsigned int wj1 = tab[j4.y];
        const unsigned int wj2 = tab[j4.z];
        const unsigned int wj3 = tab[j4.w];
        const float zpi = fmaf((float)(wi_ >> 7), qs, qb);
        const float Zi  = (float)(wi_ & 0x7Fu);
        const float zpj0 = fmaf((float)(wj0 >> 7), qs, qb), Zj0 = (float)(wj0 & 0x7Fu);
        const float zpj1 = fmaf((float)(wj1 >> 7), qs, qb), Zj1 = (float)(wj1 & 0x7Fu);
        const float zpj2 = fmaf((float)(wj2 >> 7), qs, qb), Zj2 = (float)(wj2 & 0x7Fu);
        const float zpj3 = fmaf((float)(wj3 >> 7), qs, qb), Zj3 = (float)(wj3 & 0x7Fu);
        const float ad0 = (zpi + zpj0) * (m4.x * d4.x);
        const float ad1 = (zpi + zpj1) * (m4.y * d4.y);
        const float ad2 = (zpi + zpj2) * (m4.z * d4.z);
        const float ad3 = (zpi + zpj3) * (m4.w * d4.w);
        const float f0 = exp2f(fmaf(e1, ad0, l1)) + exp2f(fmaf(e2, ad0, l2))
                       + exp2f(fmaf(e3, ad0, l3)) + exp2f(fmaf(e4, ad0, l4));
        const float f1 = exp2f(fmaf(e1, ad1, l1)) + exp2f(fmaf(e2, ad1, l2))
                       + exp2f(fmaf(e3, ad1, l3)) + exp2f(fmaf(e4, ad1, l4));
        const float f2 = exp2f(fmaf(e1, ad2, l1)) + exp2f(fmaf(e2, ad2, l2))
                       + exp2f(fmaf(e3, ad2, l3)) + exp2f(fmaf(e4, ad2, l4));
        const float f3 = exp2f(fmaf(e1, ad3, l1)) + exp2f(fmaf(e2, ad3, l2))
                       + exp2f(fmaf(e3, ad3, l3)) + exp2f(fmaf(e4, ad3, l4));
        acc += f0 * (Zi * Zj0 * m4.x) * __builtin_amdgcn_rcpf(d4.x);
        acc += f1 * (Zi * Zj1 * m4.y) * __builtin_amdgcn_rcpf(d4.y);
        acc += f2 * (Zi * Zj2 * m4.z) * __builtin_amdgcn_rcpf(d4.z);
        acc += f3 * (Zi * Zj3 * m4.w) * __builtin_amdgcn_rcpf(d4.w);
    }

    // epilogue: two iterations, waits 3/0, no restage
    asm volatile("s_waitcnt vmcnt(3)" ::: "memory");
    BODY(ITERS - 2); ++it;
    asm volatile("s_waitcnt vmcnt(0)" ::: "memory");
    BODY(ITERS - 1);

    // reduce: wave shuffle, cross-wave via reused stage LDS, one atomic
    #pragma unroll
    for (int off = 32; off > 0; off >>= 1) acc += __shfl_down(acc, off);
    __syncthreads();                        // all waves done (vmcnt drained)
    float* wred = (float*)&stage[0][0][0];  // reuse (all ring traffic done)
    if (lane == 0) wred[w] = acc;
    __syncthreads();
    if (tid == 0) {
        float t = 0.f;
        #pragma unroll
        for (int i = 0; i < WPB; ++i) t += wred[i];
        atomicAdd(&out[b], t);
    }
}

// ---------------- fallback (generic shapes, not used in bench) ----------------
__global__ void zbl_fallback(const int* __restrict__ neighbors,
                             const float* __restrict__ mask,
                             const float* __restrict__ dist,
                             const unsigned short* __restrict__ packed,
                             const float* __restrict__ scal,
                             float* __restrict__ out,
                             int N, int K, int epb, int total_edges)
{
    const int e = blockIdx.x * blockDim.x + threadIdx.x;
    if (e >= total_edges) return;
    const float e1 = scal[5], e2 = scal[6], e3 = scal[7], e4 = scal[8];
    const float qb = scal[9], qs = scal[10];
    const float l1 = scal[11], l2 = scal[12], l3 = scal[13], l4 = scal[14];
    const int b = e / epb;
    const int n = (e - b * epb) / K;
    const unsigned int wi = packed[(size_t)b * N + n];
    const unsigned int wj = packed[(size_t)b * N + neighbors[e]];
    const float zpi = fmaf((float)(wi >> 7), qs, qb);
    const float zpj = fmaf((float)(wj >> 7), qs, qb);
    const float Zi = (float)(wi & 0x7Fu), Zj = (float)(wj & 0x7Fu);
    const float m = mask[e], d = dist[e];
    const float ad = (zpi + zpj) * (m * d);
    const float f = exp2f(fmaf(e1, ad, l1)) + exp2f(fmaf(e2, ad, l2))
                  + exp2f(fmaf(e3, ad, l3)) + exp2f(fmaf(e4, ad, l4));
    const float corr = (m != 0.f) ? (f * Zi * Zj * m / d) : 0.f;
    if (corr != 0.f) atomicAdd(&out[b], corr);
}

extern "C" void kernel_launch(void* const* d_in, const int* in_sizes, int n_in,
                              void* d_out, int out_size, void* d_ws, size_t ws_size,
                              hipStream_t stream) {
    const int*   neighbors = (const int*)  d_in[0];
    const float* nb_mask   = (const float*)d_in[1];
    const int*   zn        = (const int*)  d_in[2];
    const float* dist      = (const float*)d_in[3];
    const float* adiv = (const float*)d_in[4];
    const float* apow = (const float*)d_in[5];
    const float* c1 = (const float*)d_in[6];
    const float* c2 = (const float*)d_in[7];
    const float* c3 = (const float*)d_in[8];
    const float* c4 = (const float*)d_in[9];
    const float* a1 = (const float*)d_in[10];
    const float* a2 = (const float*)d_in[11];
    const float* a3 = (const float*)d_in[12];
    const float* a4 = (const float*)d_in[13];

    const int total_edges = in_sizes[0];   // B*N*K
    const int total_atoms = in_sizes[2];   // B*N
    const int B = out_size;                // [B,1] fp32 output
    const int N = total_atoms / B;
    const int K = total_edges / total_atoms;
    const int epb = N * K;

    float*          scal   = (float*)d_ws;                         // 15 f32
    unsigned short* packed = (unsigned short*)((char*)d_ws + 64);  // B*N u16

    hipMemsetAsync(d_out, 0, (size_t)out_size * sizeof(float), stream);

    {
        const int threads = 256;
        const int blocks = (total_atoms + threads - 1) / threads;
        zbl_pre<<<blocks, threads, 0, stream>>>(zn, adiv, apow, c1, c2, c3, c4,
                                                a1, a2, a3, a4,
                                                packed, scal, total_atoms);
    }

    int kshift = 0;
    while ((1 << kshift) < K && kshift < 30) kshift++;
    const bool kpow2 = ((1 << kshift) == K);

    const int span_block = WPB * GRAN * ITERS;          // 16384 edges/block
    const bool fast = kpow2 && (kshift >= 2) && (N % 8 == 0) && (N <= 8192) &&
                      (epb % span_block == 0) &&
                      ((size_t)(64 + (size_t)total_atoms * 2) <= ws_size);
    if (fast) {
        const int bpb = epb / span_block;               // blocks per batch
        dim3 grid(bpb, B);
        zbl_main14<<<grid, 256, (size_t)N * 2, stream>>>(
            neighbors, nb_mask, dist, packed, scal, (float*)d_out,
            N, kshift, epb);
    } else {
        const int threads = 256;
        const int blocks = (total_edges + threads - 1) / threads;
        zbl_fallback<<<blocks, threads, 0, stream>>>(
            neighbors, nb_mask, dist, packed, scal, (float*)d_out,
            N, K, epb, total_edges);
    }
}

// Round 15
// 52.454 us; speedup vs baseline: 1.1034x; 1.0632x over previous
//
#include <hip/hip_runtime.h>

// ZBL repulsion energy: out[b] = sum_{n,k} KEHALF * f(a*d) * Zi*Zj*mask / d
// B=16, N=8192, K=128 in the bench (shapes derived from in_sizes).
//
// Round-15 = R8/R12 schedule with ALL per-iteration addressing strength-
// reduced away (R14 post-mortem: ~75% of the 28us absolute VALU issue is
// addressing/loop overhead, not compute):
//  - per-lane global src pointer (lane<16/32/48 select + (lane&15)*16) is
//    computed ONCE; advanced by one 64-bit add (+256B) per iteration.
//  - one per-lane LDS byte address; #pragma unroll 4 makes slot = it&3
//    compile-time so all ds_reads use offset: immediates (0..2816).
//  - uniform row atom index = row_w + (it >> kshift6), kshift6 = kshift-6.
//  - ring/waits identical to R12: depth-4, restage-previous, steady
//    vmcnt(2), epilogue 2/1/0; 512 thr, LDS 40960B -> 4 blocks/CU.

#define KEHALF_F 7.199822675975274f
#define LOG2E_F  1.4426950408889634f
#define DEPTH    4
#define GRAN     64       // edges per wave-iteration
#define WPB      8        // waves per block (512 threads)
#define SLOTB    768      // 256B idx + 256B mask + 256B dist
#define ITERS    32

__device__ __forceinline__ float softplus_f(float x) {
    return (x > 20.f) ? x : log1pf(__expf(x));
}

// ---------------- precompute: scalars + packed u16 per-atom table ----------------
// scal: [5..8]=e_i(=-sp(a_i)*log2e) [9]=qb [10]=qs [11..14]=log2(w_i*KEHALF)
__global__ void zbl_pre(const int* __restrict__ zn,
                        const float* __restrict__ adiv,
                        const float* __restrict__ apow,
                        const float* __restrict__ c1, const float* __restrict__ c2,
                        const float* __restrict__ c3, const float* __restrict__ c4,
                        const float* __restrict__ a1, const float* __restrict__ a2,
                        const float* __restrict__ a3, const float* __restrict__ a4,
                        unsigned short* __restrict__ packed, float* __restrict__ scal,
                        int total_atoms)
{
    int i = blockIdx.x * blockDim.x + threadIdx.x;
    const float spa = softplus_f(apow[0]);
    const float sad = softplus_f(adiv[0]);
    const float qb  = sad;                                  // Z=1 -> zps=sad
    const float qmax = sad * __expf(spa * __logf(94.f));
    const float qs  = (qmax - qb) * (1.f / 511.f);
    if (i == 0) {
        float s1 = softplus_f(c1[0]), s2 = softplus_f(c2[0]);
        float s3 = softplus_f(c3[0]), s4 = softplus_f(c4[0]);
        float inv = KEHALF_F / (s1 + s2 + s3 + s4);         // fold KEHALF
        float w1 = s1 * inv, w2 = s2 * inv, w3 = s3 * inv, w4 = s4 * inv;
        scal[0] = sad;
        scal[1] = w1; scal[2] = w2; scal[3] = w3; scal[4] = w4;
        scal[5] = -softplus_f(a1[0]) * LOG2E_F;             // exp2 exponents
        scal[6] = -softplus_f(a2[0]) * LOG2E_F;
        scal[7] = -softplus_f(a3[0]) * LOG2E_F;
        scal[8] = -softplus_f(a4[0]) * LOG2E_F;
        scal[9]  = qb;
        scal[10] = qs;
        scal[11] = __log2f(w1);                             // weight -> exponent
        scal[12] = __log2f(w2);
        scal[13] = __log2f(w3);
        scal[14] = __log2f(w4);
    }
    if (i < total_atoms) {
        unsigned int Z = (unsigned int)zn[i];
        float Zf = (float)Z;
        float zps = sad * __expf(spa * __logf(Zf));         // sp(adiv) * Z^sp(apow)
        float qf = (zps - qb) / qs;
        int q = (int)(qf + 0.5f);
        if (q < 0) q = 0;
        if (q > 511) q = 511;
        packed[i] = (unsigned short)(((unsigned)q << 7) | (Z & 0x7Fu));
    }
}

// ---------------- main: depth-4 ring, zero-VALU addressing ----------------
extern __shared__ unsigned short tab[];   // N u16 (dynamic, after static)

__global__ __launch_bounds__(512, 8) void zbl_main15(
        const int*            __restrict__ neighbors,
        const float*          __restrict__ mask,
        const float*          __restrict__ dist,
        const unsigned short* __restrict__ packed,
        const float*          __restrict__ scal,
        float*                __restrict__ out,
        int N, int kshift6, int epb)
{
    __shared__ char stage[WPB][DEPTH][SLOTB];   // 24576 B static

    const int tid  = threadIdx.x;
    const int w    = tid >> 6;
    const int lane = tid & 63;
    const int b    = blockIdx.y;

    // wave's contiguous edge span within batch b
    const int rw = (blockIdx.x * WPB + w) * (ITERS * GRAN);
    const size_t ebase = (size_t)b * epb + (size_t)rw;
    const int*   nb_ = neighbors + ebase;
    const float* mk_ = mask      + ebase;
    const float* ds_ = dist      + ebase;

    // per-lane global source pointer, computed ONCE (advanced in the loop)
    const char* gsrc = (lane < 16) ? (const char*)nb_
                     : (lane < 32) ? (const char*)mk_
                                   : (const char*)ds_;
    gsrc += (size_t)((lane & 15) * 16);

    // per-lane LDS slot-read base (slot 0 of this wave)
    const char* sbase = &stage[w][0][0] + (lane << 2);

    // uniform row base index (rw divisible by 2^kshift for our shapes)
    const int row_w = rw >> (kshift6 + 6);

    // 1) tab global loads first (oldest in vmem queue)
    const uint4* s4 = (const uint4*)(packed + (size_t)b * N);
    const int n8 = N >> 3;                      // # of uint4 (<= 1024)
    uint4 tv0, tv1;
    const bool h0 = (tid < n8);
    const bool h1 = (tid + 512 < n8);
    if (h0) tv0 = s4[tid];
    if (h1) tv1 = s4[tid + 512];

    // 2) ring prologue: stage slots 0..3 via immediate offsets
    if (lane < 48) {
        __builtin_amdgcn_global_load_lds(
            (const __attribute__((address_space(1))) void*)(gsrc),
            (__attribute__((address_space(3))) void*)(&stage[w][0][0]), 16, 0, 0);
        __builtin_amdgcn_global_load_lds(
            (const __attribute__((address_space(1))) void*)(gsrc + 256),
            (__attribute__((address_space(3))) void*)(&stage[w][1][0]), 16, 0, 0);
        __builtin_amdgcn_global_load_lds(
            (const __attribute__((address_space(1))) void*)(gsrc + 512),
            (__attribute__((address_space(3))) void*)(&stage[w][2][0]), 16, 0, 0);
        __builtin_amdgcn_global_load_lds(
            (const __attribute__((address_space(1))) void*)(gsrc + 768),
            (__attribute__((address_space(3))) void*)(&stage[w][3][0]), 16, 0, 0);
    }
    gsrc += 1024;                                // next data to stage (iter 4)

    // 3) write tab to LDS, then barrier
    {
        uint4* t4 = (uint4*)tab;
        if (h0) t4[tid] = tv0;
        if (h1) t4[tid + 512] = tv1;
    }
    const float e1 = scal[5],  e2 = scal[6],  e3 = scal[7],  e4 = scal[8];
    const float qb = scal[9],  qs = scal[10];
    const float l1 = scal[11], l2 = scal[12], l3 = scal[13], l4 = scal[14];
    __syncthreads();

    float acc = 0.f;

#define BODY(it) do {                                                             \
    const char* sp = sbase + ((it) & (DEPTH - 1)) * SLOTB;                        \
    const int   ji = *(const int*)  (sp);                                         \
    const float mm = *(const float*)(sp + 256);                                   \
    const float dd = *(const float*)(sp + 512);                                   \
    const unsigned int wj_ = tab[ji];                                             \
    const unsigned int wi_ = tab[row_w + ((it) >> kshift6)];                      \
    const float zpi = fmaf((float)(wi_ >> 7), qs, qb);                            \
    const float Zi  = (float)(wi_ & 0x7Fu);                                       \
    const float zpj = fmaf((float)(wj_ >> 7), qs, qb);                            \
    const float Zj  = (float)(wj_ & 0x7Fu);                                       \
    const float zz = Zi * Zj * mm;                                                \
    const float ad = (zpi + zpj) * (mm * dd);                                     \
    const float f = exp2f(fmaf(e1, ad, l1)) + exp2f(fmaf(e2, ad, l2))             \
                  + exp2f(fmaf(e3, ad, l3)) + exp2f(fmaf(e4, ad, l4));            \
    acc += f * zz * __builtin_amdgcn_rcpf(dd);                                    \
} while (0)

    // it = 0 (peeled: nothing to restage)
    asm volatile("s_waitcnt vmcnt(3)" ::: "memory");
    BODY(0);

    // main loop it = 1..ITERS-DEPTH: restage previous slot for it+3
    #pragma unroll 4
    for (int it = 1; it <= ITERS - DEPTH; ++it) {
        asm volatile("s_waitcnt vmcnt(2)" ::: "memory");     // slot 'it' landed
        if (lane < 48) {
            __builtin_amdgcn_global_load_lds(
                (const __attribute__((address_space(1))) void*)gsrc,
                (__attribute__((address_space(3))) void*)
                    (&stage[w][(it - 1) & (DEPTH - 1)][0]), 16, 0, 0);
        }
        gsrc += 256;
        BODY(it);
    }

    // epilogue: it = 29,30,31 (no restage), tightening counts
    asm volatile("s_waitcnt vmcnt(2)" ::: "memory");
    BODY(ITERS - 3);
    asm volatile("s_waitcnt vmcnt(1)" ::: "memory");
    BODY(ITERS - 2);
    asm volatile("s_waitcnt vmcnt(0)" ::: "memory");
    BODY(ITERS - 1);
#undef BODY

    // reduce: wave shuffle, then cross-wave via reused stage LDS, one atomic
    #pragma unroll
    for (int off = 32; off > 0; off >>= 1) acc += __shfl_down(acc, off);
    __syncthreads();                        // all waves done (vmcnt drained)
    float* wred = (float*)&stage[0][0][0];  // reuse (all ring traffic done)
    if (lane == 0) wred[w] = acc;
    __syncthreads();
    if (tid == 0) {
        float t = 0.f;
        #pragma unroll
        for (int i = 0; i < WPB; ++i) t += wred[i];
        atomicAdd(&out[b], t);
    }
}

// ---------------- fallback (generic shapes, not used in bench) ----------------
__global__ void zbl_fallback(const int* __restrict__ neighbors,
                             const float* __restrict__ mask,
                             const float* __restrict__ dist,
                             const unsigned short* __restrict__ packed,
                             const float* __restrict__ scal,
                             float* __restrict__ out,
                             int N, int K, int epb, int total_edges)
{
    const int e = blockIdx.x * blockDim.x + threadIdx.x;
    if (e >= total_edges) return;
    const float e1 = scal[5], e2 = scal[6], e3 = scal[7], e4 = scal[8];
    const float qb = scal[9], qs = scal[10];
    const float l1 = scal[11], l2 = scal[12], l3 = scal[13], l4 = scal[14];
    const int b = e / epb;
    const int n = (e - b * epb) / K;
    const unsigned int wi = packed[(size_t)b * N + n];
    const unsigned int wj = packed[(size_t)b * N + neighbors[e]];
    const float zpi = fmaf((float)(wi >> 7), qs, qb);
    const float zpj = fmaf((float)(wj >> 7), qs, qb);
    const float Zi = (float)(wi & 0x7Fu), Zj = (float)(wj & 0x7Fu);
    const float m = mask[e], d = dist[e];
    const float ad = (zpi + zpj) * (m * d);
    const float f = exp2f(fmaf(e1, ad, l1)) + exp2f(fmaf(e2, ad, l2))
                  + exp2f(fmaf(e3, ad, l3)) + exp2f(fmaf(e4, ad, l4));
    const float corr = (m != 0.f) ? (f * Zi * Zj * m / d) : 0.f;
    if (corr != 0.f) atomicAdd(&out[b], corr);
}

extern "C" void kernel_launch(void* const* d_in, const int* in_sizes, int n_in,
                              void* d_out, int out_size, void* d_ws, size_t ws_size,
                              hipStream_t stream) {
    const int*   neighbors = (const int*)  d_in[0];
    const float* nb_mask   = (const float*)d_in[1];
    const int*   zn        = (const int*)  d_in[2];
    const float* dist      = (const float*)d_in[3];
    const float* adiv = (const float*)d_in[4];
    const float* apow = (const float*)d_in[5];
    const float* c1 = (const float*)d_in[6];
    const float* c2 = (const float*)d_in[7];
    const float* c3 = (const float*)d_in[8];
    const float* c4 = (const float*)d_in[9];
    const float* a1 = (const float*)d_in[10];
    const float* a2 = (const float*)d_in[11];
    const float* a3 = (const float*)d_in[12];
    const float* a4 = (const float*)d_in[13];

    const int total_edges = in_sizes[0];   // B*N*K
    const int total_atoms = in_sizes[2];   // B*N
    const int B = out_size;                // [B,1] fp32 output
    const int N = total_atoms / B;
    const int K = total_edges / total_atoms;
    const int epb = N * K;

    float*          scal   = (float*)d_ws;                         // 15 f32
    unsigned short* packed = (unsigned short*)((char*)d_ws + 64);  // B*N u16

    hipMemsetAsync(d_out, 0, (size_t)out_size * sizeof(float), stream);

    {
        const int threads = 256;
        const int blocks = (total_atoms + threads - 1) / threads;
        zbl_pre<<<blocks, threads, 0, stream>>>(zn, adiv, apow, c1, c2, c3, c4,
                                                a1, a2, a3, a4,
                                                packed, scal, total_atoms);
    }

    int kshift = 0;
    while ((1 << kshift) < K && kshift < 30) kshift++;
    const bool kpow2 = ((1 << kshift) == K);

    const int span_block = WPB * GRAN * ITERS;          // 16384 edges/block
    const bool fast = kpow2 && (kshift >= 6) && (N % 8 == 0) && (N <= 8192) &&
                      (epb % span_block == 0) &&
                      ((size_t)(64 + (size_t)total_atoms * 2) <= ws_size);
    if (fast) {
        const int bpb = epb / span_block;               // blocks per batch
        dim3 grid(bpb, B);
        zbl_main15<<<grid, 512, (size_t)N * 2, stream>>>(
            neighbors, nb_mask, dist, packed, scal, (float*)d_out,
            N, kshift - 6, epb);
    } else {
        const int threads = 256;
        const int blocks = (total_edges + threads - 1) / threads;
        zbl_fallback<<<blocks, threads, 0, stream>>>(
            neighbors, nb_mask, dist, packed, scal, (float*)d_out,
            N, K, epb, total_edges);
    }
}